// Round 4
// baseline (321.187 us; speedup 1.0000x reference)
//
#include <hip/hip_runtime.h>
#include <math.h>

#define NPTS 8192
#define NB 2
#define NROWS (NB * NPTS)
#define KNN 16
#define KEEP 5          // per-lane kept candidates per row-list

// pass1 geometry: 1024-thread blocks, 16 waves x 4 rows = 64 rows/block
#define P1_G 4
#define P1_WAVES 16
#define P1_ROWS (P1_WAVES * P1_G)          // 64
#define P1_BLOCKS (NROWS / P1_ROWS)        // 256
#define P1_PER_BATCH (P1_BLOCKS / NB)      // 128
#define STEPS (NPTS / 64)                  // 128

#define INF_BITS 0x7F800000u

__device__ __forceinline__ float sqd3(float qx, float qy, float qz, float4 c) {
  float dx = qx - c.x, dy = qy - c.y, dz = qz - c.z;
  return fmaf(dx, dx, fmaf(dy, dy, dz * dz));
}

// Branchless insert into ascending sorted-KEEP list: 2 ops per level.
__device__ __forceinline__ void ins5(float (&m)[KEEP], float d) {
#pragma unroll
  for (int k = 0; k < KEEP; ++k) {
    float lo = fminf(m[k], d);
    d = fmaxf(m[k], d);
    m[k] = lo;
  }
}

// Full ascending bitonic sort of one value per lane across the 64-lane wave.
__device__ __forceinline__ float bitonic_sort64(float v, int lane) {
#pragma unroll
  for (int k = 2; k <= 64; k <<= 1) {
#pragma unroll
    for (int j = k >> 1; j >= 1; j >>= 1) {
      float o = __shfl_xor(v, j, 64);
      bool up = ((lane & k) == 0);
      bool lower = ((lane & j) == 0);
      float mn = fminf(v, o), mx = fmaxf(v, o);
      v = (up == lower) ? mn : mx;
    }
  }
  return v;
}

// From per-lane sorted m[KEEP], select the wave-global 16 smallest (exact
// unless `bad`): compact all kept values <= tau (tau = 16th-smallest lane-min,
// so >=16 distinct candidates <= tau) into wave-private LDS via ballot/mbcnt
// ranking, then one bitonic sort-64. Returns lane r's r-th smallest (r<16).
// bad := compact overflow OR some lane may have discarded a value < final[15].
__device__ __forceinline__ float select16(const float (&m)[KEEP], float tau,
                                          float* buf, int lane, bool& bad) {
  int tot = 0;
  int idx[KEEP];
#pragma unroll
  for (int k = 0; k < KEEP; ++k) {
    unsigned long long mk = __ballot(m[k] <= tau);
    int pre = __builtin_amdgcn_mbcnt_hi(
        (unsigned)(mk >> 32), __builtin_amdgcn_mbcnt_lo((unsigned)mk, 0));
    idx[k] = tot + pre;
    tot += __popcll(mk);
  }
#pragma unroll
  for (int k = 0; k < KEEP; ++k)
    if (m[k] <= tau && idx[k] < 64) buf[idx[k]] = m[k];
  float v = (lane < tot) ? buf[lane] : INFINITY;  // same-wave: no barrier
  v = bitonic_sort64(v, lane);
  float f15 = __shfl(v, 15, 64);
  bad = (tot > 64) || (__ballot(m[KEEP - 1] <= f15) != 0ull);
  return v;
}

// Pad [N,3] points to float4 for aligned dwordx4 loads.
__global__ __launch_bounds__(256) void repack_kernel(
    const float* __restrict__ yp, const float* __restrict__ yt,
    float4* __restrict__ P4, float4* __restrict__ T4) {
  int i = blockIdx.x * 256 + threadIdx.x;
  if (i < NROWS) {
    P4[i] = make_float4(yp[3 * i], yp[3 * i + 1], yp[3 * i + 2], 0.0f);
    T4[i] = make_float4(yt[3 * i], yt[3 * i + 1], yt[3 * i + 2], 0.0f);
  }
}

// Fused pass: single scan computes, per true-point row: exact minrow, exact
// sorted 16-NN vs pred AND vs true (via per-lane top-5 + tau-compaction) ->
// density contribution in-kernel; column minima (mincol) ride along via LDS
// atomicMin. Rows whose top-5 filter can't prove exactness are flagged.
__global__ __launch_bounds__(1024, 4) void pass1_kernel(
    const float4* __restrict__ P4, const float4* __restrict__ T4,
    float* __restrict__ minrow_arr, float* __restrict__ density_arr,
    unsigned* __restrict__ colmin_part, unsigned* __restrict__ rowflag) {
  __shared__ unsigned colmin[NPTS];        // 32 KB
  __shared__ float cbuf[P1_WAVES][64];     // 4 KB wave-private compact buffers
  const int wave = threadIdx.x >> 6, lane = threadIdx.x & 63;
  const int r0 = blockIdx.x * P1_ROWS + wave * P1_G;
  const int b = r0 >> 13;
  const int i0 = r0 & (NPTS - 1);
  const float4* Pb = P4 + ((size_t)b << 13);
  const float4* Tb = T4 + ((size_t)b << 13);

  for (int u = threadIdx.x; u < NPTS; u += 1024) colmin[u] = INF_BITS;

  float qx[P1_G], qy[P1_G], qz[P1_G], mP[P1_G][KEEP], mT[P1_G][KEEP];
#pragma unroll
  for (int r = 0; r < P1_G; ++r) {
    float4 q = Tb[i0 + r];
    qx[r] = q.x; qy[r] = q.y; qz[r] = q.z;
#pragma unroll
    for (int k = 0; k < KEEP; ++k) { mP[r][k] = INFINITY; mT[r][k] = INFINITY; }
  }
  __syncthreads();

  float4 cP = Pb[lane], cT = Tb[lane];
  for (int s = 0; s < STEPS; ++s) {
    int sn = (s + 1) & (STEPS - 1);
    float4 nP = Pb[sn * 64 + lane];        // prefetch next step
    float4 nT = Tb[sn * 64 + lane];
    float dP[P1_G];
#pragma unroll
    for (int r = 0; r < P1_G; ++r) dP[r] = sqd3(qx[r], qy[r], qz[r], cP);
    float cm = fminf(fminf(dP[0], dP[1]), fminf(dP[2], dP[3]));
    atomicMin(&colmin[s * 64 + lane], __float_as_uint(cm));  // 2 lanes/bank: free
#pragma unroll
    for (int r = 0; r < P1_G; ++r) ins5(mP[r], dP[r]);
#pragma unroll
    for (int r = 0; r < P1_G; ++r) ins5(mT[r], sqd3(qx[r], qy[r], qz[r], cT));
    cP = nP; cT = nT;
  }
  __syncthreads();

  // block-partial column minima -> ws
  unsigned* part = colmin_part + (size_t)blockIdx.x * NPTS;
  for (int u = threadIdx.x; u < NPTS; u += 1024) part[u] = colmin[u];

  // per-row epilogue (wave-private; no barriers)
#pragma unroll 1
  for (int r = 0; r < P1_G; ++r) {
    float smP = bitonic_sort64(mP[r][0], lane);  // sorted lane-minima (P list)
    float tauP = __shfl(smP, 15, 64);            // 16th-smallest lane-min
    bool badP;
    float sP = select16(mP[r], tauP, cbuf[wave], lane, badP);
    float smT = bitonic_sort64(mT[r][0], lane);
    float tauT = __shfl(smT, 15, 64);
    bool badT;
    float sT = select16(mT[r], tauT, cbuf[wave], lane, badT);
    float term = (lane < KNN) ? fabsf(sqrtf(sP) - sqrtf(sT)) : 0.0f;
#pragma unroll
    for (int s = 1; s < 64; s <<= 1) term += __shfl_xor(term, s, 64);
    if (lane == 0) {
      minrow_arr[r0 + r] = sqrtf(smP);           // lane 0 holds exact global min
      density_arr[r0 + r] = term;
      rowflag[r0 + r] = (badP || badT) ? 1u : 0u;
    }
  }
}

// Guaranteed-exact per-row recompute (fires only for flagged rows; P ~ 1e-5).
__device__ float exact16_rowlist(const float4* __restrict__ base,
                                 float qx, float qy, float qz, int lane) {
  float a[KNN];
#pragma unroll
  for (int k = 0; k < KNN; ++k) a[k] = INFINITY;
  for (int s = 0; s < STEPS; ++s) {
    float d = sqd3(qx, qy, qz, base[s * 64 + lane]);
    if (d < a[KNN - 1]) {
      a[KNN - 1] = d;
#pragma unroll
      for (int k = KNN - 1; k > 0; --k) {
        float lo = fminf(a[k - 1], a[k]);
        float hi = fmaxf(a[k - 1], a[k]);
        a[k - 1] = lo; a[k] = hi;
      }
    }
  }
  float res = INFINITY;
#pragma unroll 1
  for (int r = 0; r < KNN; ++r) {
    float v = a[0];
    int idx = lane;
#pragma unroll
    for (int s = 1; s < 64; s <<= 1) {
      float ov = __shfl_xor(v, s, 64);
      int oi = __shfl_xor(idx, s, 64);
      bool take = (ov < v) || (ov == v && oi < idx);
      v = take ? ov : v;
      idx = take ? oi : idx;
    }
    if (lane == r) res = v;
    if (lane == idx) {
#pragma unroll
      for (int k = 0; k < KNN - 1; ++k) a[k] = a[k + 1];
      a[KNN - 1] = INFINITY;
    }
  }
  return res;
}

// Tail: blocks [0,64) combine per-block column-min partials -> mincol;
// blocks [64,128): one wave checks 64 row flags, recomputes flagged rows.
__global__ __launch_bounds__(256) void tail_kernel(
    const float4* __restrict__ P4, const float4* __restrict__ T4,
    const unsigned* __restrict__ colmin_part, float* __restrict__ mincol_arr,
    const unsigned* __restrict__ rowflag, float* __restrict__ density_arr) {
  if (blockIdx.x < 64) {
    int idx = blockIdx.x * 256 + threadIdx.x;   // 0 .. NROWS-1
    int b = idx >> 13, j = idx & (NPTS - 1);
    const unsigned* base = colmin_part + (size_t)b * P1_PER_BATCH * NPTS + j;
    unsigned m = INF_BITS;
#pragma unroll 4
    for (int p = 0; p < P1_PER_BATCH; ++p) m = min(m, base[(size_t)p * NPTS]);
    mincol_arr[idx] = sqrtf(__uint_as_float(m));
  } else {
    const int lane = threadIdx.x & 63;
    const int wv = (blockIdx.x - 64) * 4 + (threadIdx.x >> 6);  // 0..255
    const int base = wv * 64;
    unsigned fl = rowflag[base + lane];
    unsigned long long mask = __ballot(fl != 0u);
    while (mask) {                              // wave-uniform loop
      int rr = __ffsll(mask) - 1;
      mask &= mask - 1;
      int row = base + rr;
      int b = row >> 13, i = row & (NPTS - 1);
      const float4* Pb = P4 + ((size_t)b << 13);
      const float4* Tb = T4 + ((size_t)b << 13);
      float4 q = Tb[i];
      float sP = exact16_rowlist(Pb, q.x, q.y, q.z, lane);
      float sT = exact16_rowlist(Tb, q.x, q.y, q.z, lane);
      float term = (lane < KNN) ? fabsf(sqrtf(sP) - sqrtf(sT)) : 0.0f;
#pragma unroll
      for (int s = 1; s < 64; s <<= 1) term += __shfl_xor(term, s, 64);
      if (lane == 0) density_arr[row] = term;
    }
  }
}

// Deterministic single-block reduction -> 3 outputs.
__global__ __launch_bounds__(256) void finalize_kernel(
    const float* __restrict__ minrow_arr, const float* __restrict__ mincol_arr,
    const float* __restrict__ density_arr, float* __restrict__ out) {
  __shared__ double s1[256], s2[256], s3[256];
  const int t = threadIdx.x;
  double a = 0.0, b = 0.0, c = 0.0;
  for (int idx = t; idx < NROWS; idx += 256) {
    a += (double)minrow_arr[idx];
    b += (double)mincol_arr[idx];
    c += (double)density_arr[idx];
  }
  s1[t] = a; s2[t] = b; s3[t] = c;
  __syncthreads();
  for (int off = 128; off > 0; off >>= 1) {
    if (t < off) { s1[t] += s1[t + off]; s2[t] += s2[t + off]; s3[t] += s3[t + off]; }
    __syncthreads();
  }
  if (t == 0) {
    double shape = 0.5 * (s1[0] + s2[0]) / (double)NROWS;
    double dens = s3[0] / ((double)NROWS * KNN);
    out[0] = (float)(shape + dens);  // data_loss
    out[1] = (float)shape;           // shape_loss
    out[2] = (float)dens;            // density_loss
  }
}

extern "C" void kernel_launch(void* const* d_in, const int* in_sizes, int n_in,
                              void* d_out, int out_size, void* d_ws, size_t ws_size,
                              hipStream_t stream) {
  (void)in_sizes; (void)n_in; (void)out_size; (void)ws_size;
  const float* yp = (const float*)d_in[0];  // y_pred [B, N, 3]
  const float* yt = (const float*)d_in[1];  // y_true [B, N, 3]
  float* ws = (float*)d_ws;
  float4* P4 = (float4*)ws;                           // NROWS float4
  float4* T4 = (float4*)(ws + 4 * NROWS);             // NROWS float4
  float* minrow_arr = ws + 8 * NROWS;                 // NROWS
  float* mincol_arr = minrow_arr + NROWS;
  float* density_arr = mincol_arr + NROWS;
  unsigned* rowflag = (unsigned*)(density_arr + NROWS);          // NROWS
  unsigned* colmin_part = rowflag + NROWS;            // P1_BLOCKS*NPTS u32 (8 MB)
  float* out = (float*)d_out;

  repack_kernel<<<NROWS / 256, 256, 0, stream>>>(yp, yt, P4, T4);
  pass1_kernel<<<P1_BLOCKS, 1024, 0, stream>>>(P4, T4, minrow_arr, density_arr,
                                               colmin_part, rowflag);
  tail_kernel<<<128, 256, 0, stream>>>(P4, T4, colmin_part, mincol_arr,
                                       rowflag, density_arr);
  finalize_kernel<<<1, 256, 0, stream>>>(minrow_arr, mincol_arr, density_arr, out);
}

// Round 5
// 201.892 us; speedup vs baseline: 1.5909x; 1.5909x over previous
//
#include <hip/hip_runtime.h>
#include <math.h>

#define NPTS 8192
#define NB 2
#define NROWS (NB * NPTS)
#define KNN 16
#define CAP 64        // collect capacity per row per list
#define STEPS (NPTS / 64)                  // 128

// pass1 geometry: 1024-thread blocks, 16 waves x 4 rows = 64 rows/block
#define P1_G 4
#define P1_ROWS 64
#define P1_BLOCKS (NROWS / P1_ROWS)        // 256
#define P1_PER_BATCH (P1_BLOCKS / NB)      // 128

// knn geometry: 256-thread blocks, 4 waves x 4 rows = 16 rows/block,
// plus 64 trailing blocks that do the colmin combine.
#define K_G 4
#define K_ROWS 16
#define K_BLOCKS (NROWS / K_ROWS)          // 1024
#define CMB_BLOCKS 64

#define INF_BITS 0x7F800000u

__device__ __forceinline__ float sqd3(float qx, float qy, float qz, float4 c) {
  float dx = qx - c.x, dy = qy - c.y, dz = qz - c.z;
  return fmaf(dx, dx, fmaf(dy, dy, dz * dz));
}

// Full ascending bitonic sort of one value per lane across the 64-lane wave.
__device__ __forceinline__ float bitonic_sort64(float v, int lane) {
#pragma unroll
  for (int k = 2; k <= 64; k <<= 1) {
#pragma unroll
    for (int j = k >> 1; j >= 1; j >>= 1) {
      float o = __shfl_xor(v, j, 64);
      bool up = ((lane & k) == 0);
      bool lower = ((lane & j) == 0);
      float mn = fminf(v, o), mx = fmaxf(v, o);
      v = (up == lower) ? mn : mx;
    }
  }
  return v;
}

// Pad [N,3] points to float4 for aligned dwordx4 loads.
__global__ __launch_bounds__(256) void repack_kernel(
    const float* __restrict__ yp, const float* __restrict__ yt,
    float4* __restrict__ P4, float4* __restrict__ T4) {
  int i = blockIdx.x * 256 + threadIdx.x;
  if (i < NROWS) {
    P4[i] = make_float4(yp[3 * i], yp[3 * i + 1], yp[3 * i + 2], 0.0f);
    T4[i] = make_float4(yt[3 * i], yt[3 * i + 1], yt[3 * i + 2], 0.0f);
  }
}

// Pass 1: per true-point row, per-lane min over 128 candidates for both lists
// (sorted lane-minima -> exact minrow + provable 16-NN bound tau: the 16
// smallest lane-minima are 16 distinct candidates <= tau). Column minima
// (mincol) ride along via LDS atomicMin -> per-block partial in ws.
// 2-step unrolled: 4 global loads in flight, halved loop overhead.
__global__ __launch_bounds__(1024) void pass1_kernel(
    const float4* __restrict__ P4, const float4* __restrict__ T4,
    float* __restrict__ tauP, float* __restrict__ tauT,
    float* __restrict__ minrow_arr, unsigned* __restrict__ colmin_part) {
  __shared__ unsigned colmin[NPTS];   // 32 KB, uint bits of nonneg float
  const int wave = threadIdx.x >> 6, lane = threadIdx.x & 63;
  const int r0 = blockIdx.x * P1_ROWS + wave * P1_G;
  const int b = r0 >> 13;
  const int i0 = r0 & (NPTS - 1);
  const float4* Pb = P4 + ((size_t)b << 13);
  const float4* Tb = T4 + ((size_t)b << 13);

  for (int u = threadIdx.x; u < NPTS; u += 1024) colmin[u] = INF_BITS;

  float qx[P1_G], qy[P1_G], qz[P1_G], mP[P1_G], mT[P1_G];
#pragma unroll
  for (int r = 0; r < P1_G; ++r) {
    float4 q = Tb[i0 + r];
    qx[r] = q.x; qy[r] = q.y; qz[r] = q.z;
    mP[r] = INFINITY; mT[r] = INFINITY;
  }
  __syncthreads();

  float4 cP0 = Pb[lane], cP1 = Pb[64 + lane];
  float4 cT0 = Tb[lane], cT1 = Tb[64 + lane];
  for (int s = 0; s < STEPS; s += 2) {
    int sn0 = (s + 2) & (STEPS - 1), sn1 = (s + 3) & (STEPS - 1);
    float4 nP0 = Pb[sn0 * 64 + lane], nP1 = Pb[sn1 * 64 + lane];
    float4 nT0 = Tb[sn0 * 64 + lane], nT1 = Tb[sn1 * 64 + lane];
    float d0[P1_G], d1[P1_G];
#pragma unroll
    for (int r = 0; r < P1_G; ++r) {
      d0[r] = sqd3(qx[r], qy[r], qz[r], cP0);
      mP[r] = fminf(mP[r], d0[r]);
      d1[r] = sqd3(qx[r], qy[r], qz[r], cP1);
      mP[r] = fminf(mP[r], d1[r]);
    }
    float cm0 = fminf(fminf(d0[0], d0[1]), fminf(d0[2], d0[3]));
    float cm1 = fminf(fminf(d1[0], d1[1]), fminf(d1[2], d1[3]));
    atomicMin(&colmin[s * 64 + lane], __float_as_uint(cm0));        // 2 lanes/bank: free
    atomicMin(&colmin[(s + 1) * 64 + lane], __float_as_uint(cm1));
#pragma unroll
    for (int r = 0; r < P1_G; ++r) {
      mT[r] = fminf(mT[r], sqd3(qx[r], qy[r], qz[r], cT0));
      mT[r] = fminf(mT[r], sqd3(qx[r], qy[r], qz[r], cT1));
    }
    cP0 = nP0; cP1 = nP1; cT0 = nT0; cT1 = nT1;
  }
  __syncthreads();

  // block-partial column minima -> ws
  unsigned* part = colmin_part + (size_t)blockIdx.x * NPTS;
  for (int u = threadIdx.x; u < NPTS; u += 1024) part[u] = colmin[u];

  // per-row epilogue: sort 64 lane-minima
#pragma unroll 1
  for (int r = 0; r < P1_G; ++r) {
    float v = bitonic_sort64(mP[r], lane);
    if (lane == 0) minrow_arr[r0 + r] = sqrtf(v);   // exact global min
    if (lane == 15) tauP[r0 + r] = v;               // 16th-smallest lane-min
    float v2 = bitonic_sort64(mT[r], lane);
    if (lane == 15) tauT[r0 + r] = v2;
  }
}

// Guaranteed-exact fallback (fires only if >CAP candidates under tau; P~0).
__device__ float exact16_rowlist(const float4* __restrict__ base,
                                 float qx, float qy, float qz, int lane) {
  float a[KNN];
#pragma unroll
  for (int k = 0; k < KNN; ++k) a[k] = INFINITY;
  for (int s = 0; s < STEPS; ++s) {
    float d = sqd3(qx, qy, qz, base[s * 64 + lane]);
    if (d < a[KNN - 1]) {
      a[KNN - 1] = d;
#pragma unroll
      for (int k = KNN - 1; k > 0; --k) {
        float lo = fminf(a[k - 1], a[k]);
        float hi = fmaxf(a[k - 1], a[k]);
        a[k - 1] = lo; a[k] = hi;
      }
    }
  }
  float res = INFINITY;
#pragma unroll 1
  for (int r = 0; r < KNN; ++r) {
    float v = a[0];
    int idx = lane;
#pragma unroll
    for (int s = 1; s < 64; s <<= 1) {
      float ov = __shfl_xor(v, s, 64);
      int oi = __shfl_xor(idx, s, 64);
      bool take = (ov < v) || (ov == v && oi < idx);
      v = take ? ov : v;
      idx = take ? oi : idx;
    }
    if (lane == r) res = v;
    if (lane == idx) {
#pragma unroll
      for (int k = 0; k < KNN - 1; ++k) a[k] = a[k + 1];
      a[KNN - 1] = INFINITY;
    }
  }
  return res;
}

// Pass 2: collect candidates with d <= tau per row per list (4 rows/wave,
// wave-uniform __any skip, wave-private LDS, zero barriers), then one bitonic
// sort-64 -> exact ascending 16-NN of both lists -> density contribution.
// Trailing CMB_BLOCKS blocks combine the pass1 column-min partials -> mincol.
__global__ __launch_bounds__(256) void knn_kernel(
    const float4* __restrict__ P4, const float4* __restrict__ T4,
    const float* __restrict__ tauP, const float* __restrict__ tauT,
    const unsigned* __restrict__ colmin_part, float* __restrict__ mincol_arr,
    float* __restrict__ density_arr) {
  if (blockIdx.x >= K_BLOCKS) {
    // colmin combine: 64 blocks x 256 threads cover NROWS columns
    int idx = (blockIdx.x - K_BLOCKS) * 256 + threadIdx.x;
    int b = idx >> 13, j = idx & (NPTS - 1);
    const unsigned* base = colmin_part + (size_t)b * P1_PER_BATCH * NPTS + j;
    unsigned m = INF_BITS;
#pragma unroll 8
    for (int p = 0; p < P1_PER_BATCH; ++p) m = min(m, base[(size_t)p * NPTS]);
    mincol_arr[idx] = sqrtf(__uint_as_float(m));
    return;
  }
  __shared__ float col[K_ROWS][2][CAP];   // 8 KB
  __shared__ int cnt[K_ROWS][2];
  const int wave = threadIdx.x >> 6, lane = threadIdx.x & 63;
  const int row0 = blockIdx.x * K_ROWS;
  const int b = row0 >> 13;
  const int i0 = row0 & (NPTS - 1);
  const float4* Pb = P4 + ((size_t)b << 13);
  const float4* Tb = T4 + ((size_t)b << 13);
  const int wr = wave * K_G;

  if (lane < 2 * K_G) cnt[wr + (lane >> 1)][lane & 1] = 0;  // wave-private init

  float qx[K_G], qy[K_G], qz[K_G], tP[K_G], tT[K_G];
#pragma unroll
  for (int r = 0; r < K_G; ++r) {
    float4 q = Tb[i0 + wr + r];
    qx[r] = q.x; qy[r] = q.y; qz[r] = q.z;
    tP[r] = tauP[row0 + wr + r];
    tT[r] = tauT[row0 + wr + r];
  }

  float4 cP = Pb[lane], cT = Tb[lane];
  for (int s = 0; s < STEPS; ++s) {
    int sn = (s + 1) & (STEPS - 1);
    float4 nP = Pb[sn * 64 + lane];
    float4 nT = Tb[sn * 64 + lane];
    float dP[K_G];
    bool hP = false;
#pragma unroll
    for (int r = 0; r < K_G; ++r) {
      dP[r] = sqd3(qx[r], qy[r], qz[r], cP);
      hP = hP || (dP[r] <= tP[r]);
    }
    if (__any(hP)) {                       // wave-uniform skip: ~50% of steps
#pragma unroll
      for (int r = 0; r < K_G; ++r) {
        if (dP[r] <= tP[r]) {
          int ix = atomicAdd(&cnt[wr + r][0], 1);
          if (ix < CAP) col[wr + r][0][ix] = dP[r];
        }
      }
    }
    float dT[K_G];
    bool hT = false;
#pragma unroll
    for (int r = 0; r < K_G; ++r) {
      dT[r] = sqd3(qx[r], qy[r], qz[r], cT);
      hT = hT || (dT[r] <= tT[r]);
    }
    if (__any(hT)) {
#pragma unroll
      for (int r = 0; r < K_G; ++r) {
        if (dT[r] <= tT[r]) {
          int ix = atomicAdd(&cnt[wr + r][1], 1);
          if (ix < CAP) col[wr + r][1][ix] = dT[r];
        }
      }
    }
    cP = nP; cT = nT;
  }

#pragma unroll 1
  for (int r = 0; r < K_G; ++r) {
    int cPc = cnt[wr + r][0];
    int cTc = cnt[wr + r][1];
    float vP = (lane < cPc) ? col[wr + r][0][lane] : INFINITY;
    float vT = (lane < cTc) ? col[wr + r][1][lane] : INFINITY;
    float sP = bitonic_sort64(vP, lane);
    float sT = bitonic_sort64(vT, lane);
    if (cPc > CAP) sP = exact16_rowlist(Pb, qx[r], qy[r], qz[r], lane);
    if (cTc > CAP) sT = exact16_rowlist(Tb, qx[r], qy[r], qz[r], lane);
    float term = (lane < KNN) ? fabsf(sqrtf(sP) - sqrtf(sT)) : 0.0f;
#pragma unroll
    for (int s = 1; s < 64; s <<= 1) term += __shfl_xor(term, s, 64);
    if (lane == 0) density_arr[row0 + wr + r] = term;
  }
}

// Deterministic single-block reduction -> 3 outputs.
__global__ __launch_bounds__(256) void finalize_kernel(
    const float* __restrict__ minrow_arr, const float* __restrict__ mincol_arr,
    const float* __restrict__ density_arr, float* __restrict__ out) {
  __shared__ double s1[256], s2[256], s3[256];
  const int t = threadIdx.x;
  double a = 0.0, b = 0.0, c = 0.0;
  for (int idx = t; idx < NROWS; idx += 256) {
    a += (double)minrow_arr[idx];
    b += (double)mincol_arr[idx];
    c += (double)density_arr[idx];
  }
  s1[t] = a; s2[t] = b; s3[t] = c;
  __syncthreads();
  for (int off = 128; off > 0; off >>= 1) {
    if (t < off) { s1[t] += s1[t + off]; s2[t] += s2[t + off]; s3[t] += s3[t + off]; }
    __syncthreads();
  }
  if (t == 0) {
    double shape = 0.5 * (s1[0] + s2[0]) / (double)NROWS;
    double dens = s3[0] / ((double)NROWS * KNN);
    out[0] = (float)(shape + dens);  // data_loss
    out[1] = (float)shape;           // shape_loss
    out[2] = (float)dens;            // density_loss
  }
}

extern "C" void kernel_launch(void* const* d_in, const int* in_sizes, int n_in,
                              void* d_out, int out_size, void* d_ws, size_t ws_size,
                              hipStream_t stream) {
  (void)in_sizes; (void)n_in; (void)out_size; (void)ws_size;
  const float* yp = (const float*)d_in[0];  // y_pred [B, N, 3]
  const float* yt = (const float*)d_in[1];  // y_true [B, N, 3]
  float* ws = (float*)d_ws;
  float4* P4 = (float4*)ws;                           // NROWS float4
  float4* T4 = (float4*)(ws + 4 * NROWS);             // NROWS float4
  float* tauP = ws + 8 * NROWS;                       // NROWS
  float* tauT = tauP + NROWS;
  float* minrow_arr = tauT + NROWS;
  float* mincol_arr = minrow_arr + NROWS;
  float* density_arr = mincol_arr + NROWS;
  unsigned* colmin_part = (unsigned*)(density_arr + NROWS);  // P1_BLOCKS*NPTS u32 (8 MB)
  float* out = (float*)d_out;

  repack_kernel<<<NROWS / 256, 256, 0, stream>>>(yp, yt, P4, T4);
  pass1_kernel<<<P1_BLOCKS, 1024, 0, stream>>>(P4, T4, tauP, tauT, minrow_arr, colmin_part);
  knn_kernel<<<K_BLOCKS + CMB_BLOCKS, 256, 0, stream>>>(P4, T4, tauP, tauT,
                                                        colmin_part, mincol_arr, density_arr);
  finalize_kernel<<<1, 256, 0, stream>>>(minrow_arr, mincol_arr, density_arr, out);
}